// Round 1
// baseline (229.225 us; speedup 1.0000x reference)
//
#include <hip/hip_runtime.h>
#include <hip/hip_bf16.h>
#include <math.h>

#define N 4096
#define D 1024
#define NCHUNK 16      // column chunks across grid
#define ROWBLOCKS 32   // N / BM
#define BM 128         // rows per block (4 waves x 32)
#define BN 64          // columns per inner iteration (4 tiles of 16)
#define KC 128         // K staged per LDS chunk

typedef __bf16 bf16x8 __attribute__((ext_vector_type(8)));
typedef __bf16 bf16x4 __attribute__((ext_vector_type(4)));
typedef float f32x4 __attribute__((ext_vector_type(4)));

// ---------------- init: zero the two scalar accumulators ----------------
__global__ void init_kernel(float* accs) {
  if (threadIdx.x < 2) accs[threadIdx.x] = 0.0f;
}

// ---------------- block-wide reduction (256 threads, 4 waves) ----------------
__device__ __forceinline__ float block_reduce(float v, bool ismax, float* buf, int tid) {
  #pragma unroll
  for (int o = 32; o > 0; o >>= 1) {
    float w = __shfl_xor(v, o);
    v = ismax ? fmaxf(v, w) : (v + w);
  }
  __syncthreads();
  if ((tid & 63) == 0) buf[tid >> 6] = v;
  __syncthreads();
  float r = buf[0];
  #pragma unroll
  for (int i = 1; i < 4; i++) r = ismax ? fmaxf(r, buf[i]) : (r + buf[i]);
  return r;
}

// ---------------- prep: normalize rows to bf16 + fused row-KL(target||predicted) ----------------
__global__ __launch_bounds__(256) void prep_kernel(const float* __restrict__ tgt,
                                                   const float* __restrict__ prd,
                                                   __bf16* __restrict__ tn,
                                                   __bf16* __restrict__ pn,
                                                   float* __restrict__ acc2) {
  __shared__ float buf[4];
  const int row = blockIdx.x, tid = threadIdx.x;
  float4 tv = ((const float4*)(tgt + (size_t)row * D))[tid];
  float4 pv = ((const float4*)(prd + (size_t)row * D))[tid];
  float t_[4] = {tv.x, tv.y, tv.z, tv.w};
  float p_[4] = {pv.x, pv.y, pv.z, pv.w};
  float ss_t = 0.f, ss_p = 0.f, mx_t = -1e30f, mx_p = -1e30f;
  #pragma unroll
  for (int j = 0; j < 4; j++) {
    ss_t += t_[j] * t_[j]; ss_p += p_[j] * p_[j];
    mx_t = fmaxf(mx_t, t_[j]); mx_p = fmaxf(mx_p, p_[j]);
  }
  ss_t = block_reduce(ss_t, false, buf, tid);
  ss_p = block_reduce(ss_p, false, buf, tid);
  mx_t = block_reduce(mx_t, true, buf, tid);
  mx_p = block_reduce(mx_p, true, buf, tid);
  float rnt = 1.0f / fmaxf(sqrtf(ss_t), 1e-8f);
  float rnp = 1.0f / fmaxf(sqrtf(ss_p), 1e-8f);
  bf16x4 to, po;
  #pragma unroll
  for (int j = 0; j < 4; j++) { to[j] = (__bf16)(t_[j] * rnt); po[j] = (__bf16)(p_[j] * rnp); }
  *(bf16x4*)(tn + (size_t)row * D + tid * 4) = to;
  *(bf16x4*)(pn + (size_t)row * D + tid * 4) = po;
  // KL(softmax(t_row) || softmax(p_row)) = S/lt - (mt - mp + log lt - log lp)
  float et = 0.f, ep = 0.f, sv = 0.f;
  #pragma unroll
  for (int j = 0; j < 4; j++) {
    float e = expf(t_[j] - mx_t);
    et += e; sv += e * (t_[j] - p_[j]);
    ep += expf(p_[j] - mx_p);
  }
  et = block_reduce(et, false, buf, tid);
  ep = block_reduce(ep, false, buf, tid);
  sv = block_reduce(sv, false, buf, tid);
  if (tid == 0) {
    float kl = sv / et - (mx_t - mx_p + logf(et) - logf(ep));
    atomicAdd(acc2, kl * (1.0f / (float)N));
  }
}

// ---------------- fused flash-style KL over the two Gram matrices ----------------
// grid = ROWBLOCKS(32) * NCHUNK(16) blocks of 256 threads (4 waves x 32 rows).
// Each block handles 128 rows x 256 cols; stats merged exactly in combine_kernel.
__global__ __launch_bounds__(256, 2) void kl1_kernel(const __bf16* __restrict__ tn,
                                                     const __bf16* __restrict__ pn,
                                                     float* __restrict__ partials) {
  __shared__ __align__(16) __bf16 bsh[2 * 64 * KC];  // 32 KB: [mat][64 cols][KC k]
  const int tid = threadIdx.x;
  const int wid = tid >> 6, lane = tid & 63;
  const int g = lane >> 4, lr = lane & 15;
  const int rowblock = blockIdx.x & (ROWBLOCKS - 1);
  const int chunk = blockIdx.x >> 5;
  const int rowbase = rowblock * BM + wid * 32;
  const int colbase = chunk * (N / NCHUNK);

  // per-row online stats: rows (g*4 + r) within each 16-row tile rt
  float m1[2][4], l1[2][4], m2[2][4], l2[2][4], S[2][4];
  #pragma unroll
  for (int rt = 0; rt < 2; rt++)
    #pragma unroll
    for (int r = 0; r < 4; r++) {
      m1[rt][r] = -1e30f; m2[rt][r] = -1e30f;
      l1[rt][r] = 0.f; l2[rt][r] = 0.f; S[rt][r] = 0.f;
    }

  const int srow = tid >> 2;   // staging: col-row 0..63
  const int skq = tid & 3;     // staging: k-quad
  const __bf16* mats[2] = {tn, pn};

  for (int ci = 0; ci < 4; ci++) {
    const int cb = colbase + ci * BN;
    f32x4 acc[2][4][2];  // [rt][ct][mat]
    #pragma unroll
    for (int rt = 0; rt < 2; rt++)
      #pragma unroll
      for (int ct = 0; ct < 4; ct++)
        #pragma unroll
        for (int m = 0; m < 2; m++)
          acc[rt][ct][m] = (f32x4){0.f, 0.f, 0.f, 0.f};

    for (int kc = 0; kc < D / KC; kc++) {
      __syncthreads();
      // stage B tile (64 cols x KC k, both matrices) with XOR swizzle (G4/T2)
      #pragma unroll
      for (int m = 0; m < 2; m++) {
        const __bf16* src = mats[m] + (size_t)(cb + srow) * D + kc * KC;
        #pragma unroll
        for (int i = 0; i < 4; i++) {
          int k0 = skq * 8 + i * 32;
          bf16x8 v = *(const bf16x8*)(src + k0);
          int elem = m * (64 * KC) + srow * KC + k0;
          elem ^= (srow & 7) << 3;  // byte ^= (row&7)<<4
          *(bf16x8*)(&bsh[elem]) = v;
        }
      }
      __syncthreads();
      #pragma unroll
      for (int ks = 0; ks < KC / 32; ks++) {
        const int k = kc * KC + ks * 32 + g * 8;
        bf16x8 a[2][2];
        #pragma unroll
        for (int rt = 0; rt < 2; rt++)
          #pragma unroll
          for (int m = 0; m < 2; m++)
            a[rt][m] = *(const bf16x8*)(mats[m] + (size_t)(rowbase + rt * 16 + lr) * D + k);
        #pragma unroll
        for (int ct = 0; ct < 4; ct++) {
          int be = (ct * 16 + lr) * KC + ks * 32 + g * 8;
          be ^= (lr & 7) << 3;  // same involution as write side
          #pragma unroll
          for (int m = 0; m < 2; m++) {
            bf16x8 b = *(const bf16x8*)(&bsh[m * (64 * KC) + be]);
            #pragma unroll
            for (int rt = 0; rt < 2; rt++)
              acc[rt][ct][m] =
                  __builtin_amdgcn_mfma_f32_16x16x32_bf16(a[rt][m], b, acc[rt][ct][m], 0, 0, 0);
          }
        }
      }
    }

    // online stat update over this 64-col slab
    #pragma unroll
    for (int rt = 0; rt < 2; rt++) {
      #pragma unroll
      for (int r = 0; r < 4; r++) {
        float s1v[4], s2v[4];
        #pragma unroll
        for (int ct = 0; ct < 4; ct++) { s1v[ct] = acc[rt][ct][0][r]; s2v[ct] = acc[rt][ct][1][r]; }
        float c1 = fmaxf(fmaxf(s1v[0], s1v[1]), fmaxf(s1v[2], s1v[3]));
        float c2 = fmaxf(fmaxf(s2v[0], s2v[1]), fmaxf(s2v[2], s2v[3]));
        #pragma unroll
        for (int mk = 1; mk < 16; mk <<= 1) {
          c1 = fmaxf(c1, __shfl_xor(c1, mk));
          c2 = fmaxf(c2, __shfl_xor(c2, mk));
        }
        float nm1 = fmaxf(m1[rt][r], c1);
        float nm2 = fmaxf(m2[rt][r], c2);
        float e1 = 0.f, e2 = 0.f, sl = 0.f;
        #pragma unroll
        for (int ct = 0; ct < 4; ct++) {
          float pe = expf(s1v[ct] - nm1);
          e1 += pe; sl += pe * (s1v[ct] - s2v[ct]);
          e2 += expf(s2v[ct] - nm2);
        }
        #pragma unroll
        for (int mk = 1; mk < 16; mk <<= 1) {
          e1 += __shfl_xor(e1, mk);
          e2 += __shfl_xor(e2, mk);
          sl += __shfl_xor(sl, mk);
        }
        float sc1 = expf(m1[rt][r] - nm1);
        float sc2 = expf(m2[rt][r] - nm2);
        l1[rt][r] = l1[rt][r] * sc1 + e1;
        S[rt][r] = S[rt][r] * sc1 + sl;
        m1[rt][r] = nm1;
        l2[rt][r] = l2[rt][r] * sc2 + e2;
        m2[rt][r] = nm2;
      }
    }
  }

  // write per-(row, chunk) partial stats {m1,l1,m2,l2,S}
  if (lr == 0) {
    #pragma unroll
    for (int rt = 0; rt < 2; rt++)
      #pragma unroll
      for (int r = 0; r < 4; r++) {
        int row = rowbase + rt * 16 + g * 4 + r;
        float* pp = partials + ((size_t)row * NCHUNK + chunk) * 5;
        pp[0] = m1[rt][r]; pp[1] = l1[rt][r]; pp[2] = m2[rt][r];
        pp[3] = l2[rt][r]; pp[4] = S[rt][r];
      }
  }
}

// ---------------- exact merge of per-chunk stats -> per-row KL -> mean ----------------
__global__ __launch_bounds__(256) void combine_kernel(const float* __restrict__ partials,
                                                      float* __restrict__ acc1) {
  int row = blockIdx.x * 256 + threadIdx.x;
  const float* p = partials + (size_t)row * NCHUNK * 5;
  float M1 = -1e30f, M2 = -1e30f;
  for (int c = 0; c < NCHUNK; c++) {
    M1 = fmaxf(M1, p[c * 5 + 0]);
    M2 = fmaxf(M2, p[c * 5 + 2]);
  }
  float L1 = 0.f, L2 = 0.f, Sg = 0.f;
  for (int c = 0; c < NCHUNK; c++) {
    float sc = expf(p[c * 5 + 0] - M1);
    L1 += p[c * 5 + 1] * sc;
    Sg += p[c * 5 + 4] * sc;
    L2 += p[c * 5 + 3] * expf(p[c * 5 + 2] - M2);
  }
  float kl = Sg / L1 - (M1 - M2 + logf(L1) - logf(L2));
  atomicAdd(acc1, kl * (1.0f / (float)N));
}

__global__ void final_kernel(const float* __restrict__ accs, float* __restrict__ out) {
  out[0] = accs[0] + accs[1];
}

// ---------------- launch ----------------
extern "C" void kernel_launch(void* const* d_in, const int* in_sizes, int n_in,
                              void* d_out, int out_size, void* d_ws, size_t ws_size,
                              hipStream_t stream) {
  const float* tgt = (const float*)d_in[0];
  const float* prd = (const float*)d_in[1];
  float* out = (float*)d_out;
  char* ws = (char*)d_ws;
  // workspace layout (all 16B aligned): tn 8MB | pn 8MB | partials 1.25MB | accs
  __bf16* tn = (__bf16*)ws;
  __bf16* pn = (__bf16*)(ws + 8388608);
  float* partials = (float*)(ws + 16777216);
  float* accs = (float*)(ws + 18087936);

  init_kernel<<<1, 64, 0, stream>>>(accs);
  prep_kernel<<<N, 256, 0, stream>>>(tgt, prd, tn, pn, accs + 1);
  kl1_kernel<<<ROWBLOCKS * NCHUNK, 256, 0, stream>>>(tn, pn, partials);
  combine_kernel<<<N / 256, 256, 0, stream>>>(partials, accs);
  final_kernel<<<1, 1, 0, stream>>>(accs, out);
}

// Round 2
// 178.761 us; speedup vs baseline: 1.2823x; 1.2823x over previous
//
#include <hip/hip_runtime.h>
#include <hip/hip_bf16.h>
#include <math.h>

#define N 4096
#define D 1024
#define PANEL 128
#define NPANEL 32                      // N / PANEL
#define NTRI (NPANEL * (NPANEL + 1) / 2)  // 528 upper-triangle tiles
#define BK 32

typedef __bf16 bf16x8 __attribute__((ext_vector_type(8)));
typedef __bf16 bf16x4 __attribute__((ext_vector_type(4)));
typedef float f32x4 __attribute__((ext_vector_type(4)));

// ---------------- zero the rowstats (4096*3) + 2 accumulators ----------------
__global__ void zero_kernel(float* p) {
  int i = blockIdx.x * 256 + threadIdx.x;
  if (i < N * 3 + 2) p[i] = 0.0f;
}

// ---------------- block-wide reduction (256 threads, 4 waves) ----------------
__device__ __forceinline__ float block_reduce(float v, bool ismax, float* buf, int tid) {
  #pragma unroll
  for (int o = 32; o > 0; o >>= 1) {
    float w = __shfl_xor(v, o);
    v = ismax ? fmaxf(v, w) : (v + w);
  }
  __syncthreads();
  if ((tid & 63) == 0) buf[tid >> 6] = v;
  __syncthreads();
  float r = buf[0];
  #pragma unroll
  for (int i = 1; i < 4; i++) r = ismax ? fmaxf(r, buf[i]) : (r + buf[i]);
  return r;
}

// ---------------- prep: normalize rows to bf16 + fused row-KL(target||predicted) ----------------
__global__ __launch_bounds__(256) void prep_kernel(const float* __restrict__ tgt,
                                                   const float* __restrict__ prd,
                                                   __bf16* __restrict__ tn,
                                                   __bf16* __restrict__ pn,
                                                   float* __restrict__ acc2) {
  __shared__ float buf[4];
  const int row = blockIdx.x, tid = threadIdx.x;
  float4 tv = ((const float4*)(tgt + (size_t)row * D))[tid];
  float4 pv = ((const float4*)(prd + (size_t)row * D))[tid];
  float t_[4] = {tv.x, tv.y, tv.z, tv.w};
  float p_[4] = {pv.x, pv.y, pv.z, pv.w};
  float ss_t = 0.f, ss_p = 0.f, mx_t = -1e30f, mx_p = -1e30f;
  #pragma unroll
  for (int j = 0; j < 4; j++) {
    ss_t += t_[j] * t_[j]; ss_p += p_[j] * p_[j];
    mx_t = fmaxf(mx_t, t_[j]); mx_p = fmaxf(mx_p, p_[j]);
  }
  ss_t = block_reduce(ss_t, false, buf, tid);
  ss_p = block_reduce(ss_p, false, buf, tid);
  mx_t = block_reduce(mx_t, true, buf, tid);
  mx_p = block_reduce(mx_p, true, buf, tid);
  float rnt = 1.0f / fmaxf(sqrtf(ss_t), 1e-8f);
  float rnp = 1.0f / fmaxf(sqrtf(ss_p), 1e-8f);
  bf16x4 to, po;
  #pragma unroll
  for (int j = 0; j < 4; j++) { to[j] = (__bf16)(t_[j] * rnt); po[j] = (__bf16)(p_[j] * rnp); }
  *(bf16x4*)(tn + (size_t)row * D + tid * 4) = to;
  *(bf16x4*)(pn + (size_t)row * D + tid * 4) = po;
  // KL(softmax(t_row) || softmax(p_row)) = S/lt - (mt - mp + log lt - log lp)
  float et = 0.f, ep = 0.f, sv = 0.f;
  #pragma unroll
  for (int j = 0; j < 4; j++) {
    float e = __expf(t_[j] - mx_t);
    et += e; sv += e * (t_[j] - p_[j]);
    ep += __expf(p_[j] - mx_p);
  }
  et = block_reduce(et, false, buf, tid);
  ep = block_reduce(ep, false, buf, tid);
  sv = block_reduce(sv, false, buf, tid);
  if (tid == 0) {
    float kl = sv / et - (mx_t - mx_p + __logf(et) - __logf(ep));
    atomicAdd(acc2, kl * (1.0f / (float)N));
  }
}

// ---------------- upper-triangle Gram tiles, fixed-max (=1) softmax stats ----------------
// 528 blocks of 256 threads (4 waves, 2x2). Tile = 128x128, BK=32, both mats.
// LDS: A[2][128][32] + B[2][128][32] bf16 = 32KB, global_load_lds with
// pre-swizzled source (slot = g ^ ((row>>1)&3)) -> conflict-free ds_read_b128.
__global__ __launch_bounds__(256, 2) void gram_kernel(const __bf16* __restrict__ tn,
                                                      const __bf16* __restrict__ pn,
                                                      float* __restrict__ rowstats) {
  __shared__ __align__(16) uint8_t smem[32768];
  const int tid = threadIdx.x;
  const int wid = tid >> 6, lane = tid & 63;
  const int g = lane >> 4, lr = lane & 15;
  const int wr = wid >> 1, wc = wid & 1;

  // bijective XCD swizzle (528 % 8 == 0), then triangular decode
  int bid = blockIdx.x;
  int swz = (bid & 7) * (NTRI / 8) + (bid >> 3);
  int rb = 0, rem = swz;
  while (rem >= NPANEL - rb) { rem -= NPANEL - rb; rb++; }
  int cc = rb + rem;
  const int rowbase = rb * PANEL, colbase = cc * PANEL;

  f32x4 acc[4][4][2];  // [rt][ct][mat]
  #pragma unroll
  for (int rt = 0; rt < 4; rt++)
    #pragma unroll
    for (int ct = 0; ct < 4; ct++)
      #pragma unroll
      for (int m = 0; m < 2; m++)
        acc[rt][ct][m] = (f32x4){0.f, 0.f, 0.f, 0.f};

  for (int kc = 0; kc < D / BK; kc++) {
    __syncthreads();  // previous chunk's reads complete before overwrite
    // stage A(128 rows) + B(128 cols) x 32k x 2 mats = 32KB: 8 x 16B per thread
    #pragma unroll
    for (int i = 0; i < 8; i++) {
      int L = i * 256 + tid;          // 16B-slot index in [0, 2048)
      int isB = L >> 10;              // 0 = A region, 1 = B region
      int mat = (L >> 9) & 1;
      int rc = (L >> 2) & 127;        // row (A) or col (B) within tile
      int slot = L & 3;
      int gk = slot ^ ((rc >> 1) & 3);  // inverse swizzle -> source k-group
      const __bf16* base = mat ? pn : tn;
      const __bf16* src = base + (size_t)((isB ? colbase : rowbase) + rc) * D + kc * BK + gk * 8;
      __builtin_amdgcn_global_load_lds(
          (const __attribute__((address_space(1))) void*)src,
          (__attribute__((address_space(3))) void*)(smem + L * 16), 16, 0, 0);
    }
    __syncthreads();  // drain vmcnt + make LDS visible

    bf16x8 a[4][2];
    #pragma unroll
    for (int rt = 0; rt < 4; rt++) {
      int row = wr * 64 + rt * 16 + lr;
      int sw = (row >> 1) & 3;
      #pragma unroll
      for (int m = 0; m < 2; m++)
        a[rt][m] = *(const bf16x8*)(smem + m * 8192 + row * 64 + ((g ^ sw) << 4));
    }
    #pragma unroll
    for (int ct = 0; ct < 4; ct++) {
      int col = wc * 64 + ct * 16 + lr;
      int sw = (col >> 1) & 3;
      #pragma unroll
      for (int m = 0; m < 2; m++) {
        bf16x8 b = *(const bf16x8*)(smem + 16384 + m * 8192 + col * 64 + ((g ^ sw) << 4));
        #pragma unroll
        for (int rt = 0; rt < 4; rt++)
          acc[rt][ct][m] =
              __builtin_amdgcn_mfma_f32_16x16x32_bf16(a[rt][m], b, acc[rt][ct][m], 0, 0, 0);
      }
    }
  }

  // ---- epilogue: fixed-max (m=1) stats; plain sums + atomics ----
  // C/D layout: row = tile + g*4 + r, col = tile + lr  (verified round 1)
  // row-direction stats (all blocks): rows of rb-panel over cols of cc-panel
  #pragma unroll
  for (int rt = 0; rt < 4; rt++) {
    #pragma unroll
    for (int r = 0; r < 4; r++) {
      float e1 = 0.f, e2 = 0.f, sl = 0.f;
      #pragma unroll
      for (int ct = 0; ct < 4; ct++) {
        float s1 = acc[rt][ct][0][r], s2 = acc[rt][ct][1][r];
        float p = __expf(s1 - 1.0f);
        e1 += p; sl += p * (s1 - s2);
        e2 += __expf(s2 - 1.0f);
      }
      #pragma unroll
      for (int mk = 1; mk < 16; mk <<= 1) {
        e1 += __shfl_xor(e1, mk);
        e2 += __shfl_xor(e2, mk);
        sl += __shfl_xor(sl, mk);
      }
      if (lr == 0) {
        int row = rowbase + wr * 64 + rt * 16 + g * 4 + r;
        atomicAdd(&rowstats[row * 3 + 0], e1);
        atomicAdd(&rowstats[row * 3 + 1], e2);
        atomicAdd(&rowstats[row * 3 + 2], sl);
      }
    }
  }
  // col-direction stats (off-diagonal): transpose tile feeds rows of cc-panel
  if (rb != cc) {
    #pragma unroll
    for (int ct = 0; ct < 4; ct++) {
      float e1 = 0.f, e2 = 0.f, sl = 0.f;
      #pragma unroll
      for (int rt = 0; rt < 4; rt++)
        #pragma unroll
        for (int r = 0; r < 4; r++) {
          float s1 = acc[rt][ct][0][r], s2 = acc[rt][ct][1][r];
          float p = __expf(s1 - 1.0f);
          e1 += p; sl += p * (s1 - s2);
          e2 += __expf(s2 - 1.0f);
        }
      e1 += __shfl_xor(e1, 16); e2 += __shfl_xor(e2, 16); sl += __shfl_xor(sl, 16);
      e1 += __shfl_xor(e1, 32); e2 += __shfl_xor(e2, 32); sl += __shfl_xor(sl, 32);
      if (g == 0) {
        int col = colbase + wc * 64 + ct * 16 + lr;
        atomicAdd(&rowstats[col * 3 + 0], e1);
        atomicAdd(&rowstats[col * 3 + 1], e2);
        atomicAdd(&rowstats[col * 3 + 2], sl);
      }
    }
  }
}

// ---------------- per-row KL from stats -> mean ----------------
__global__ __launch_bounds__(256) void finalize_kernel(const float* __restrict__ rowstats,
                                                       float* __restrict__ acc1) {
  __shared__ float buf[4];
  int row = blockIdx.x * 256 + threadIdx.x;
  float e1 = rowstats[row * 3 + 0];
  float e2 = rowstats[row * 3 + 1];
  float sl = rowstats[row * 3 + 2];
  float kl = sl / e1 - (__logf(e1) - __logf(e2));
  kl = block_reduce(kl, false, buf, threadIdx.x);
  if (threadIdx.x == 0) atomicAdd(acc1, kl * (1.0f / (float)N));
}

__global__ void final_kernel(const float* __restrict__ accs, float* __restrict__ out) {
  out[0] = accs[0] + accs[1];
}

// ---------------- launch ----------------
extern "C" void kernel_launch(void* const* d_in, const int* in_sizes, int n_in,
                              void* d_out, int out_size, void* d_ws, size_t ws_size,
                              hipStream_t stream) {
  const float* tgt = (const float*)d_in[0];
  const float* prd = (const float*)d_in[1];
  float* out = (float*)d_out;
  char* ws = (char*)d_ws;
  // ws layout: tn 8MB | pn 8MB | rowstats 48KB | accs 8B
  __bf16* tn = (__bf16*)ws;
  __bf16* pn = (__bf16*)(ws + 8388608);
  float* rowstats = (float*)(ws + 16777216);
  float* accs = (float*)(ws + 16777216 + 49152);

  zero_kernel<<<(N * 3 + 2 + 255) / 256, 256, 0, stream>>>(rowstats);
  prep_kernel<<<N, 256, 0, stream>>>(tgt, prd, tn, pn, accs + 1);
  gram_kernel<<<NTRI, 256, 0, stream>>>(tn, pn, rowstats);
  finalize_kernel<<<N / 256, 256, 0, stream>>>(rowstats, accs);
  final_kernel<<<1, 1, 0, stream>>>(accs, out);
}

// Round 3
// 172.594 us; speedup vs baseline: 1.3281x; 1.0357x over previous
//
#include <hip/hip_runtime.h>
#include <hip/hip_bf16.h>
#include <math.h>

#define N 4096
#define D 1024
#define PANEL 128
#define NPANEL 32                         // N / PANEL
#define NTRI (NPANEL * (NPANEL + 1) / 2)  // 528 upper-triangle tiles
#define BK 32

typedef __bf16 bf16x8 __attribute__((ext_vector_type(8)));
typedef __bf16 bf16x4 __attribute__((ext_vector_type(4)));
typedef float f32x4 __attribute__((ext_vector_type(4)));

// ---------------- zero rowstats (N*3) + acc2 (1) ----------------
__global__ void zero_kernel(float* p) {
  int i = blockIdx.x * 256 + threadIdx.x;
  if (i < N * 3 + 1) p[i] = 0.0f;
}

// ---------------- prep: wave-per-row normalize + fused row-KL ----------------
// 1024 blocks x 256 threads; wave w handles row blockIdx.x*4 + w. No barriers.
__global__ __launch_bounds__(256) void prep_kernel(const float* __restrict__ tgt,
                                                   const float* __restrict__ prd,
                                                   __bf16* __restrict__ tn,
                                                   __bf16* __restrict__ pn,
                                                   float* __restrict__ acc2) {
  const int wid = threadIdx.x >> 6, lane = threadIdx.x & 63;
  const int row = blockIdx.x * 4 + wid;
  const float* tr = tgt + (size_t)row * D;
  const float* pr = prd + (size_t)row * D;
  float4 tv[4], pv[4];
  #pragma unroll
  for (int j = 0; j < 4; j++) {
    tv[j] = ((const float4*)tr)[j * 64 + lane];
    pv[j] = ((const float4*)pr)[j * 64 + lane];
  }
  float ss_t = 0.f, ss_p = 0.f, mx_t = -1e30f, mx_p = -1e30f;
  #pragma unroll
  for (int j = 0; j < 4; j++) {
    float t_[4] = {tv[j].x, tv[j].y, tv[j].z, tv[j].w};
    float p_[4] = {pv[j].x, pv[j].y, pv[j].z, pv[j].w};
    #pragma unroll
    for (int k = 0; k < 4; k++) {
      ss_t += t_[k] * t_[k]; ss_p += p_[k] * p_[k];
      mx_t = fmaxf(mx_t, t_[k]); mx_p = fmaxf(mx_p, p_[k]);
    }
  }
  #pragma unroll
  for (int o = 32; o > 0; o >>= 1) {
    ss_t += __shfl_xor(ss_t, o);
    ss_p += __shfl_xor(ss_p, o);
    mx_t = fmaxf(mx_t, __shfl_xor(mx_t, o));
    mx_p = fmaxf(mx_p, __shfl_xor(mx_p, o));
  }
  float rnt = 1.0f / fmaxf(sqrtf(ss_t), 1e-8f);
  float rnp = 1.0f / fmaxf(sqrtf(ss_p), 1e-8f);
  float et = 0.f, ep = 0.f, sv = 0.f;
  #pragma unroll
  for (int j = 0; j < 4; j++) {
    float t_[4] = {tv[j].x, tv[j].y, tv[j].z, tv[j].w};
    float p_[4] = {pv[j].x, pv[j].y, pv[j].z, pv[j].w};
    bf16x4 to, po;
    #pragma unroll
    for (int k = 0; k < 4; k++) {
      to[k] = (__bf16)(t_[k] * rnt);
      po[k] = (__bf16)(p_[k] * rnp);
      float e = __expf(t_[k] - mx_t);
      et += e; sv += e * (t_[k] - p_[k]);
      ep += __expf(p_[k] - mx_p);
    }
    ((bf16x4*)(tn + (size_t)row * D))[j * 64 + lane] = to;
    ((bf16x4*)(pn + (size_t)row * D))[j * 64 + lane] = po;
  }
  #pragma unroll
  for (int o = 32; o > 0; o >>= 1) {
    et += __shfl_xor(et, o);
    ep += __shfl_xor(ep, o);
    sv += __shfl_xor(sv, o);
  }
  if (lane == 0) {
    float kl = sv / et - (mx_t - mx_p + __logf(et) - __logf(ep));
    atomicAdd(acc2, kl * (1.0f / (float)N));
  }
}

// ---------------- upper-triangle Gram tiles, fixed-max (=1) stats ----------------
// 528 blocks x 256 threads (4 waves, 2x2 of 64x64-dual). Double-buffered LDS
// (2 x 32KB), stage issued BEFORE compute, one barrier per K-iter (T3-minimum).
__global__ __launch_bounds__(256, 2) void gram_kernel(const __bf16* __restrict__ tn,
                                                      const __bf16* __restrict__ pn,
                                                      float* __restrict__ rowstats) {
  __shared__ __align__(16) uint8_t smem[65536];
  const int tid = threadIdx.x;
  const int wid = tid >> 6, lane = tid & 63;
  const int g = lane >> 4, lr = lane & 15;
  const int wr = wid >> 1, wc = wid & 1;

  // bijective XCD swizzle (528 % 8 == 0), then triangular decode
  int bid = blockIdx.x;
  int swz = (bid & 7) * (NTRI / 8) + (bid >> 3);
  int rb = 0, rem = swz;
  while (rem >= NPANEL - rb) { rem -= NPANEL - rb; rb++; }
  int cc = rb + rem;
  const int rowbase = rb * PANEL, colbase = cc * PANEL;

  // hoisted staging sources: 8 x 16B per thread covers 32KB buffer
  const __bf16* srcp[8];
  uint32_t dsto[8];
  #pragma unroll
  for (int i = 0; i < 8; i++) {
    int L = i * 256 + tid;            // 16B-slot index in [0, 2048)
    int isB = L >> 10;                // 0 = A region, 1 = B region
    int mat = (L >> 9) & 1;
    int rc = (L >> 2) & 127;          // row (A) / col (B) within tile
    int slot = L & 3;
    int gk = slot ^ ((rc >> 1) & 3);  // inverse swizzle -> source k-group
    const __bf16* base = mat ? pn : tn;
    srcp[i] = base + (size_t)((isB ? colbase : rowbase) + rc) * D + gk * 8;
    dsto[i] = (uint32_t)L * 16;
  }
  auto stage = [&](int buf, int kc) {
    #pragma unroll
    for (int i = 0; i < 8; i++)
      __builtin_amdgcn_global_load_lds(
          (const __attribute__((address_space(1))) void*)(srcp[i] + kc * BK),
          (__attribute__((address_space(3))) void*)(smem + buf * 32768 + dsto[i]), 16, 0, 0);
  };

  f32x4 acc[4][4][2];  // [rt][ct][mat]
  #pragma unroll
  for (int rt = 0; rt < 4; rt++)
    #pragma unroll
    for (int ct = 0; ct < 4; ct++)
      #pragma unroll
      for (int m = 0; m < 2; m++)
        acc[rt][ct][m] = (f32x4){0.f, 0.f, 0.f, 0.f};

  stage(0, 0);
  __syncthreads();

  #pragma unroll 2
  for (int kc = 0; kc < D / BK; kc++) {
    const int cur = kc & 1;
    if (kc < D / BK - 1) stage(cur ^ 1, kc + 1);  // prefetch next chunk

    const uint8_t* sa = smem + cur * 32768;
    bf16x8 a[4][2];
    #pragma unroll
    for (int rt = 0; rt < 4; rt++) {
      int row = wr * 64 + rt * 16 + lr;
      int sw = (row >> 1) & 3;
      #pragma unroll
      for (int m = 0; m < 2; m++)
        a[rt][m] = *(const bf16x8*)(sa + m * 8192 + row * 64 + ((g ^ sw) << 4));
    }
    #pragma unroll
    for (int ct = 0; ct < 4; ct++) {
      int col = wc * 64 + ct * 16 + lr;
      int sw = (col >> 1) & 3;
      #pragma unroll
      for (int m = 0; m < 2; m++) {
        bf16x8 b = *(const bf16x8*)(sa + 16384 + m * 8192 + col * 64 + ((g ^ sw) << 4));
        #pragma unroll
        for (int rt = 0; rt < 4; rt++)
          acc[rt][ct][m] =
              __builtin_amdgcn_mfma_f32_16x16x32_bf16(a[rt][m], b, acc[rt][ct][m], 0, 0, 0);
      }
    }
    __syncthreads();  // waits own vmcnt (prefetch) + all waves done reading cur
  }

  // ---- epilogue: fixed-max (m=1) stats; plain sums + atomics ----
  // C/D layout: row = tile + g*4 + r, col = tile + lr
  #pragma unroll
  for (int rt = 0; rt < 4; rt++) {
    #pragma unroll
    for (int r = 0; r < 4; r++) {
      float e1 = 0.f, e2 = 0.f, sl = 0.f;
      #pragma unroll
      for (int ct = 0; ct < 4; ct++) {
        float s1 = acc[rt][ct][0][r], s2 = acc[rt][ct][1][r];
        float p = __expf(s1 - 1.0f);
        e1 += p; sl += p * (s1 - s2);
        e2 += __expf(s2 - 1.0f);
      }
      #pragma unroll
      for (int mk = 1; mk < 16; mk <<= 1) {
        e1 += __shfl_xor(e1, mk);
        e2 += __shfl_xor(e2, mk);
        sl += __shfl_xor(sl, mk);
      }
      if (lr == 0) {
        int row = rowbase + wr * 64 + rt * 16 + g * 4 + r;
        atomicAdd(&rowstats[row * 3 + 0], e1);
        atomicAdd(&rowstats[row * 3 + 1], e2);
        atomicAdd(&rowstats[row * 3 + 2], sl);
      }
    }
  }
  if (rb != cc) {  // transpose contribution for off-diagonal tiles
    #pragma unroll
    for (int ct = 0; ct < 4; ct++) {
      float e1 = 0.f, e2 = 0.f, sl = 0.f;
      #pragma unroll
      for (int rt = 0; rt < 4; rt++)
        #pragma unroll
        for (int r = 0; r < 4; r++) {
          float s1 = acc[rt][ct][0][r], s2 = acc[rt][ct][1][r];
          float p = __expf(s1 - 1.0f);
          e1 += p; sl += p * (s1 - s2);
          e2 += __expf(s2 - 1.0f);
        }
      e1 += __shfl_xor(e1, 16); e2 += __shfl_xor(e2, 16); sl += __shfl_xor(sl, 16);
      e1 += __shfl_xor(e1, 32); e2 += __shfl_xor(e2, 32); sl += __shfl_xor(sl, 32);
      if (g == 0) {
        int col = colbase + wc * 64 + ct * 16 + lr;
        atomicAdd(&rowstats[col * 3 + 0], e1);
        atomicAdd(&rowstats[col * 3 + 1], e2);
        atomicAdd(&rowstats[col * 3 + 2], sl);
      }
    }
  }
}

// ---------------- single-block finalize: row KLs -> mean, + prep term ----------------
__global__ __launch_bounds__(1024) void finalize_kernel(const float* __restrict__ rowstats,
                                                        const float* __restrict__ acc2,
                                                        float* __restrict__ out) {
  __shared__ float buf[16];
  float s = 0.f;
  for (int r = threadIdx.x; r < N; r += 1024) {
    float e1 = rowstats[r * 3 + 0];
    float e2 = rowstats[r * 3 + 1];
    float sl = rowstats[r * 3 + 2];
    s += sl / e1 - (__logf(e1) - __logf(e2));
  }
  #pragma unroll
  for (int o = 32; o > 0; o >>= 1) s += __shfl_xor(s, o);
  if ((threadIdx.x & 63) == 0) buf[threadIdx.x >> 6] = s;
  __syncthreads();
  if (threadIdx.x == 0) {
    float t = 0.f;
    #pragma unroll
    for (int i = 0; i < 16; i++) t += buf[i];
    out[0] = t * (1.0f / (float)N) + acc2[0];
  }
}

// ---------------- launch ----------------
extern "C" void kernel_launch(void* const* d_in, const int* in_sizes, int n_in,
                              void* d_out, int out_size, void* d_ws, size_t ws_size,
                              hipStream_t stream) {
  const float* tgt = (const float*)d_in[0];
  const float* prd = (const float*)d_in[1];
  float* out = (float*)d_out;
  char* ws = (char*)d_ws;
  // ws layout: tn 8MB | pn 8MB | rowstats N*3 f32 | acc2 1 f32
  __bf16* tn = (__bf16*)ws;
  __bf16* pn = (__bf16*)(ws + 8388608);
  float* rowstats = (float*)(ws + 16777216);
  float* acc2 = rowstats + N * 3;

  zero_kernel<<<(N * 3 + 1 + 255) / 256, 256, 0, stream>>>(rowstats);
  prep_kernel<<<N / 4, 256, 0, stream>>>(tgt, prd, tn, pn, acc2);
  gram_kernel<<<NTRI, 256, 0, stream>>>(tn, pn, rowstats);
  finalize_kernel<<<1, 1024, 0, stream>>>(rowstats, acc2, out);
}

// Round 4
// 121.946 us; speedup vs baseline: 1.8797x; 1.4153x over previous
//
#include <hip/hip_runtime.h>
#include <hip/hip_bf16.h>
#include <math.h>

#define N 4096
#define D 1024
#define PANEL 128
#define NPANEL 32                         // N / PANEL
#define NTRI (NPANEL * (NPANEL + 1) / 2)  // 528 upper-triangle tiles
#define BK 32
#define NITER (D / BK)                    // 32 K-iters

typedef float f32x4 __attribute__((ext_vector_type(4)));

// ---------------- zero rowstats (N*3) ----------------
__global__ void zero_kernel(float* p) {
  int i = blockIdx.x * 256 + threadIdx.x;
  if (i < N * 3) p[i] = 0.0f;
}

// ---------------- prep: wave-per-row normalize -> fp8, fused row-KL (no atomics) ----------------
__global__ __launch_bounds__(256) void prep_kernel(const float* __restrict__ tgt,
                                                   const float* __restrict__ prd,
                                                   uint32_t* __restrict__ tn,
                                                   uint32_t* __restrict__ pn,
                                                   float* __restrict__ rowkl) {
  const int wid = threadIdx.x >> 6, lane = threadIdx.x & 63;
  const int row = blockIdx.x * 4 + wid;
  const float* tr = tgt + (size_t)row * D;
  const float* pr = prd + (size_t)row * D;
  float4 tv[4], pv[4];
  #pragma unroll
  for (int j = 0; j < 4; j++) {
    tv[j] = ((const float4*)tr)[j * 64 + lane];
    pv[j] = ((const float4*)pr)[j * 64 + lane];
  }
  float ss_t = 0.f, ss_p = 0.f, mx_t = -1e30f, mx_p = -1e30f;
  #pragma unroll
  for (int j = 0; j < 4; j++) {
    float t_[4] = {tv[j].x, tv[j].y, tv[j].z, tv[j].w};
    float p_[4] = {pv[j].x, pv[j].y, pv[j].z, pv[j].w};
    #pragma unroll
    for (int k = 0; k < 4; k++) {
      ss_t += t_[k] * t_[k]; ss_p += p_[k] * p_[k];
      mx_t = fmaxf(mx_t, t_[k]); mx_p = fmaxf(mx_p, p_[k]);
    }
  }
  #pragma unroll
  for (int o = 32; o > 0; o >>= 1) {
    ss_t += __shfl_xor(ss_t, o);
    ss_p += __shfl_xor(ss_p, o);
    mx_t = fmaxf(mx_t, __shfl_xor(mx_t, o));
    mx_p = fmaxf(mx_p, __shfl_xor(mx_p, o));
  }
  float rnt = 1.0f / fmaxf(sqrtf(ss_t), 1e-8f);
  float rnp = 1.0f / fmaxf(sqrtf(ss_p), 1e-8f);
  float et = 0.f, ep = 0.f, sv = 0.f;
  #pragma unroll
  for (int j = 0; j < 4; j++) {
    float t_[4] = {tv[j].x, tv[j].y, tv[j].z, tv[j].w};
    float p_[4] = {pv[j].x, pv[j].y, pv[j].z, pv[j].w};
    uint32_t tpack = 0, ppack = 0;
    tpack = __builtin_amdgcn_cvt_pk_fp8_f32(t_[0] * rnt, t_[1] * rnt, tpack, false);
    tpack = __builtin_amdgcn_cvt_pk_fp8_f32(t_[2] * rnt, t_[3] * rnt, tpack, true);
    ppack = __builtin_amdgcn_cvt_pk_fp8_f32(p_[0] * rnp, p_[1] * rnp, ppack, false);
    ppack = __builtin_amdgcn_cvt_pk_fp8_f32(p_[2] * rnp, p_[3] * rnp, ppack, true);
    tn[(size_t)row * (D / 4) + j * 64 + lane] = tpack;
    pn[(size_t)row * (D / 4) + j * 64 + lane] = ppack;
    #pragma unroll
    for (int k = 0; k < 4; k++) {
      float e = __expf(t_[k] - mx_t);
      et += e; sv += e * (t_[k] - p_[k]);
      ep += __expf(p_[k] - mx_p);
    }
  }
  #pragma unroll
  for (int o = 32; o > 0; o >>= 1) {
    et += __shfl_xor(et, o);
    ep += __shfl_xor(ep, o);
    sv += __shfl_xor(sv, o);
  }
  if (lane == 0)
    rowkl[row] = sv / et - (mx_t - mx_p + __logf(et) - __logf(ep));
}

// ---------------- upper-triangle Gram tiles, fp8, counted-vmcnt depth-3 pipeline ----------------
// 528 blocks x 256 threads (4 waves, 2x2 of 64x64-dual). LDS: 4 x 16KB circular.
// Buffer layout: [isB][mat][128 rows][32 B] ; natural layout is conflict-free for
// ds_read_b64 fragments (16 rows x 32B = 512 contiguous bytes per read).
__global__ __launch_bounds__(256, 2) void gram_kernel(const uint8_t* __restrict__ tn,
                                                      const uint8_t* __restrict__ pn,
                                                      float* __restrict__ rowstats) {
  __shared__ __align__(16) uint8_t smem[4 * 16384];
  const int tid = threadIdx.x;
  const int wid = tid >> 6, lane = tid & 63;
  const int g = lane >> 4, lr = lane & 15;
  const int wr = wid >> 1, wc = wid & 1;

  // bijective XCD swizzle (528 % 8 == 0), then triangular decode
  int bid = blockIdx.x;
  int swz = (bid & 7) * (NTRI / 8) + (bid >> 3);
  int rb = 0, rem = swz;
  while (rem >= NPANEL - rb) { rem -= NPANEL - rb; rb++; }
  int cc = rb + rem;
  const int rowbase = rb * PANEL, colbase = cc * PANEL;

  // staging: 1024 16B-slots per buffer -> 4 per thread
  const uint8_t* srcp[4];
  uint32_t dsto[4];
  #pragma unroll
  for (int i = 0; i < 4; i++) {
    int L = i * 256 + tid;            // slot in [0,1024)
    int isB = L >> 9;
    int mat = (L >> 8) & 1;
    int rc = (L >> 1) & 127;          // row (A) / col (B)
    int half = L & 1;                 // which 16B half of the 32B row-chunk
    const uint8_t* base = mat ? pn : tn;
    srcp[i] = base + (size_t)((isB ? colbase : rowbase) + rc) * D + half * 16;
    dsto[i] = (uint32_t)L * 16;
  }
  auto stage = [&](int buf, int kc) {
    #pragma unroll
    for (int i = 0; i < 4; i++)
      __builtin_amdgcn_global_load_lds(
          (const __attribute__((address_space(1))) void*)(srcp[i] + kc * BK),
          (__attribute__((address_space(3))) void*)(smem + buf * 16384 + dsto[i]), 16, 0, 0);
  };

  f32x4 acc[4][4][2];  // [rt][ct][mat]
  #pragma unroll
  for (int rt = 0; rt < 4; rt++)
    #pragma unroll
    for (int ct = 0; ct < 4; ct++)
      #pragma unroll
      for (int m = 0; m < 2; m++)
        acc[rt][ct][m] = (f32x4){0.f, 0.f, 0.f, 0.f};

  auto body = [&](int bufidx) {
    const uint8_t* sa = smem + bufidx * 16384;
    long a[4][2];
    #pragma unroll
    for (int rt = 0; rt < 4; rt++) {
      int row = wr * 64 + rt * 16 + lr;
      #pragma unroll
      for (int m = 0; m < 2; m++)
        a[rt][m] = *(const long*)(sa + m * 4096 + row * 32 + g * 8);
    }
    __builtin_amdgcn_s_setprio(1);
    #pragma unroll
    for (int ct = 0; ct < 4; ct++) {
      int col = wc * 64 + ct * 16 + lr;
      #pragma unroll
      for (int m = 0; m < 2; m++) {
        long b = *(const long*)(sa + 8192 + m * 4096 + col * 32 + g * 8);
        #pragma unroll
        for (int rt = 0; rt < 4; rt++)
          acc[rt][ct][m] =
              __builtin_amdgcn_mfma_f32_16x16x32_fp8_fp8(a[rt][m], b, acc[rt][ct][m], 0, 0, 0);
      }
    }
    __builtin_amdgcn_s_setprio(0);
  };

  // prologue: 3 stages in flight (12 vmem ops/wave)
  stage(0, 0); stage(1, 1); stage(2, 2);

  // main loop: steady-state wait vmcnt(8) -> stage(k) landed, 2 stages in flight
  for (int k = 0; k < NITER - 3; k++) {
    asm volatile("s_waitcnt vmcnt(8)" ::: "memory");
    __builtin_amdgcn_s_barrier();
    stage((k + 3) & 3, k + 3);
    body(k & 3);
  }
  // tail: k = NITER-3, NITER-2, NITER-1 (no more issues; exact counts)
  asm volatile("s_waitcnt vmcnt(8)" ::: "memory");
  __builtin_amdgcn_s_barrier();
  body((NITER - 3) & 3);
  asm volatile("s_waitcnt vmcnt(4)" ::: "memory");
  __builtin_amdgcn_s_barrier();
  body((NITER - 2) & 3);
  asm volatile("s_waitcnt vmcnt(0)" ::: "memory");
  __builtin_amdgcn_s_barrier();
  body((NITER - 1) & 3);

  // ---- epilogue: fixed-max (m=1) stats; plain sums + spread atomics ----
  // C/D layout: row = tile + g*4 + r, col = tile + lr
  #pragma unroll
  for (int rt = 0; rt < 4; rt++) {
    #pragma unroll
    for (int r = 0; r < 4; r++) {
      float e1 = 0.f, e2 = 0.f, sl = 0.f;
      #pragma unroll
      for (int ct = 0; ct < 4; ct++) {
        float s1 = acc[rt][ct][0][r], s2 = acc[rt][ct][1][r];
        float p = __expf(s1 - 1.0f);
        e1 += p; sl += p * (s1 - s2);
        e2 += __expf(s2 - 1.0f);
      }
      #pragma unroll
      for (int mk = 1; mk < 16; mk <<= 1) {
        e1 += __shfl_xor(e1, mk);
        e2 += __shfl_xor(e2, mk);
        sl += __shfl_xor(sl, mk);
      }
      if (lr == 0) {
        int row = rowbase + wr * 64 + rt * 16 + g * 4 + r;
        atomicAdd(&rowstats[row * 3 + 0], e1);
        atomicAdd(&rowstats[row * 3 + 1], e2);
        atomicAdd(&rowstats[row * 3 + 2], sl);
      }
    }
  }
  if (rb != cc) {  // transpose contribution for off-diagonal tiles
    #pragma unroll
    for (int ct = 0; ct < 4; ct++) {
      float e1 = 0.f, e2 = 0.f, sl = 0.f;
      #pragma unroll
      for (int rt = 0; rt < 4; rt++)
        #pragma unroll
        for (int r = 0; r < 4; r++) {
          float s1 = acc[rt][ct][0][r], s2 = acc[rt][ct][1][r];
          float p = __expf(s1 - 1.0f);
          e1 += p; sl += p * (s1 - s2);
          e2 += __expf(s2 - 1.0f);
        }
      e1 += __shfl_xor(e1, 16); e2 += __shfl_xor(e2, 16); sl += __shfl_xor(sl, 16);
      e1 += __shfl_xor(e1, 32); e2 += __shfl_xor(e2, 32); sl += __shfl_xor(sl, 32);
      if (g == 0) {
        int col = colbase + wc * 64 + ct * 16 + lr;
        atomicAdd(&rowstats[col * 3 + 0], e1);
        atomicAdd(&rowstats[col * 3 + 1], e2);
        atomicAdd(&rowstats[col * 3 + 2], sl);
      }
    }
  }
}

// ---------------- single-block finalize: row KLs + prep row term -> mean ----------------
__global__ __launch_bounds__(1024) void finalize_kernel(const float* __restrict__ rowstats,
                                                        const float* __restrict__ rowkl,
                                                        float* __restrict__ out) {
  __shared__ float buf[16];
  float s = 0.f;
  for (int r = threadIdx.x; r < N; r += 1024) {
    float e1 = rowstats[r * 3 + 0];
    float e2 = rowstats[r * 3 + 1];
    float sl = rowstats[r * 3 + 2];
    s += sl / e1 - (__logf(e1) - __logf(e2)) + rowkl[r];
  }
  #pragma unroll
  for (int o = 32; o > 0; o >>= 1) s += __shfl_xor(s, o);
  if ((threadIdx.x & 63) == 0) buf[threadIdx.x >> 6] = s;
  __syncthreads();
  if (threadIdx.x == 0) {
    float t = 0.f;
    #pragma unroll
    for (int i = 0; i < 16; i++) t += buf[i];
    out[0] = t * (1.0f / (float)N);
  }
}

// ---------------- launch ----------------
extern "C" void kernel_launch(void* const* d_in, const int* in_sizes, int n_in,
                              void* d_out, int out_size, void* d_ws, size_t ws_size,
                              hipStream_t stream) {
  const float* tgt = (const float*)d_in[0];
  const float* prd = (const float*)d_in[1];
  float* out = (float*)d_out;
  char* ws = (char*)d_ws;
  // ws layout: tn 4MB | pn 4MB | rowstats N*3 f32 | rowkl N f32
  uint32_t* tn = (uint32_t*)ws;
  uint32_t* pn = (uint32_t*)(ws + 4194304);
  float* rowstats = (float*)(ws + 8388608);
  float* rowkl = rowstats + N * 3;

  zero_kernel<<<(N * 3 + 255) / 256, 256, 0, stream>>>(rowstats);
  prep_kernel<<<N / 4, 256, 0, stream>>>(tgt, prd, tn, pn, rowkl);
  gram_kernel<<<NTRI, 256, 0, stream>>>((const uint8_t*)tn, (const uint8_t*)pn, rowstats);
  finalize_kernel<<<1, 1024, 0, stream>>>(rowstats, rowkl, out);
}

// Round 5
// 121.006 us; speedup vs baseline: 1.8943x; 1.0078x over previous
//
#include <hip/hip_runtime.h>
#include <hip/hip_bf16.h>
#include <math.h>

#define N 4096
#define D 1024
#define PANEL 128
#define NPANEL 32                         // N / PANEL
#define NTRI (NPANEL * (NPANEL + 1) / 2)  // 528 upper-triangle tiles
#define BK 32
#define NITER (D / BK)                    // 32 K-iters
#define PANBYTES 131072                   // one panel, one matrix: 32 kc * 4096 B

typedef float f32x4 __attribute__((ext_vector_type(4)));

// Blocked fp8 layout, per matrix:
//   off(row, kc, b) = ((row>>7)*32 + kc)*4096 + (row&127)*32 + b_phys
//   b_phys: 8B-group swizzle  b_phys = ((G ^ ((r>>2)&3))<<3) | (b&7),  G = b>>3
// -> every (panel,kc) chunk is 4KB contiguous; gram stages it sequentially.

// ---------------- zero rowstats (N*3) ----------------
__global__ void zero_kernel(float* p) {
  int i = blockIdx.x * 256 + threadIdx.x;
  if (i < N * 3) p[i] = 0.0f;
}

// ---------------- prep: wave-per-row normalize -> blocked fp8, fused row-KL ----------------
__global__ __launch_bounds__(256) void prep_kernel(const float* __restrict__ tgt,
                                                   const float* __restrict__ prd,
                                                   uint8_t* __restrict__ tn,
                                                   uint8_t* __restrict__ pn,
                                                   float* __restrict__ rowkl) {
  const int wid = threadIdx.x >> 6, lane = threadIdx.x & 63;
  const int row = blockIdx.x * 4 + wid;
  const float* tr = tgt + (size_t)row * D;
  const float* pr = prd + (size_t)row * D;
  float4 tv[4], pv[4];
  #pragma unroll
  for (int j = 0; j < 4; j++) {
    tv[j] = ((const float4*)tr)[j * 64 + lane];
    pv[j] = ((const float4*)pr)[j * 64 + lane];
  }
  float ss_t = 0.f, ss_p = 0.f, mx_t = -1e30f, mx_p = -1e30f;
  #pragma unroll
  for (int j = 0; j < 4; j++) {
    float t_[4] = {tv[j].x, tv[j].y, tv[j].z, tv[j].w};
    float p_[4] = {pv[j].x, pv[j].y, pv[j].z, pv[j].w};
    #pragma unroll
    for (int k = 0; k < 4; k++) {
      ss_t += t_[k] * t_[k]; ss_p += p_[k] * p_[k];
      mx_t = fmaxf(mx_t, t_[k]); mx_p = fmaxf(mx_p, p_[k]);
    }
  }
  #pragma unroll
  for (int o = 32; o > 0; o >>= 1) {
    ss_t += __shfl_xor(ss_t, o);
    ss_p += __shfl_xor(ss_p, o);
    mx_t = fmaxf(mx_t, __shfl_xor(mx_t, o));
    mx_p = fmaxf(mx_p, __shfl_xor(mx_p, o));
  }
  float rnt = 1.0f / fmaxf(sqrtf(ss_t), 1e-8f);
  float rnp = 1.0f / fmaxf(sqrtf(ss_p), 1e-8f);

  const int P = row >> 7, r = row & 127;
  // lane's 4 elements live in kc = j*8 + (lane>>3), logical bytes (lane&7)*4 ..+3
  const int kcsub = lane >> 3;
  const int G = (lane & 7) >> 1;                 // logical 8B-group
  const int Gs = G ^ ((r >> 2) & 3);             // swizzled group
  const int bphys = (Gs << 3) | ((lane & 1) * 4);

  float et = 0.f, ep = 0.f, sv = 0.f;
  #pragma unroll
  for (int j = 0; j < 4; j++) {
    float t_[4] = {tv[j].x, tv[j].y, tv[j].z, tv[j].w};
    float p_[4] = {pv[j].x, pv[j].y, pv[j].z, pv[j].w};
    uint32_t tpack = 0, ppack = 0;
    tpack = __builtin_amdgcn_cvt_pk_fp8_f32(t_[0] * rnt, t_[1] * rnt, tpack, false);
    tpack = __builtin_amdgcn_cvt_pk_fp8_f32(t_[2] * rnt, t_[3] * rnt, tpack, true);
    ppack = __builtin_amdgcn_cvt_pk_fp8_f32(p_[0] * rnp, p_[1] * rnp, ppack, false);
    ppack = __builtin_amdgcn_cvt_pk_fp8_f32(p_[2] * rnp, p_[3] * rnp, ppack, true);
    size_t off = ((size_t)(P * 32 + j * 8 + kcsub)) * 4096 + r * 32 + bphys;
    *(uint32_t*)(tn + off) = tpack;
    *(uint32_t*)(pn + off) = ppack;
    #pragma unroll
    for (int k = 0; k < 4; k++) {
      float e = __expf(t_[k] - mx_t);
      et += e; sv += e * (t_[k] - p_[k]);
      ep += __expf(p_[k] - mx_p);
    }
  }
  #pragma unroll
  for (int o = 32; o > 0; o >>= 1) {
    et += __shfl_xor(et, o);
    ep += __shfl_xor(ep, o);
    sv += __shfl_xor(sv, o);
  }
  if (lane == 0)
    rowkl[row] = sv / et - (mx_t - mx_p + __logf(et) - __logf(ep));
}

// ---------------- upper-triangle Gram tiles, fp8, coalesced staged, depth-3 pipeline ----------------
// 528 blocks x 256 threads (4 waves, 2x2 of 64x64-dual). LDS: 4 x 16KB circular.
// Per iter stage = 4 contiguous 4KB chunks (A-t, A-p, B-t, B-p), fully coalesced.
__global__ __launch_bounds__(256, 2) void gram_kernel(const uint8_t* __restrict__ tn,
                                                      const uint8_t* __restrict__ pn,
                                                      float* __restrict__ rowstats) {
  __shared__ __align__(16) uint8_t smem[4 * 16384];
  const int tid = threadIdx.x;
  const int wid = tid >> 6, lane = tid & 63;
  const int g = lane >> 4, lr = lane & 15;
  const int wr = wid >> 1, wc = wid & 1;

  // bijective XCD swizzle (528 % 8 == 0), then triangular decode
  int bid = blockIdx.x;
  int swz = (bid & 7) * (NTRI / 8) + (bid >> 3);
  int rb = 0, rem = swz;
  while (rem >= NPANEL - rb) { rem -= NPANEL - rb; rb++; }
  int cc = rb + rem;
  const int rowbase = rb * PANEL, colbase = cc * PANEL;

  const uint8_t* regbase[4] = {tn + (size_t)rb * PANBYTES, pn + (size_t)rb * PANBYTES,
                               tn + (size_t)cc * PANBYTES, pn + (size_t)cc * PANBYTES};
  auto stage = [&](int buf, int kc) {
    #pragma unroll
    for (int i = 0; i < 4; i++)
      __builtin_amdgcn_global_load_lds(
          (const __attribute__((address_space(1))) void*)(regbase[i] + kc * 4096 + tid * 16),
          (__attribute__((address_space(3))) void*)(smem + buf * 16384 + i * 4096 + tid * 16),
          16, 0, 0);
  };

  f32x4 acc[4][4][2];  // [rt][ct][mat]
  #pragma unroll
  for (int rt = 0; rt < 4; rt++)
    #pragma unroll
    for (int ct = 0; ct < 4; ct++)
      #pragma unroll
      for (int m = 0; m < 2; m++)
        acc[rt][ct][m] = (f32x4){0.f, 0.f, 0.f, 0.f};

  auto body = [&](int bufidx) {
    const uint8_t* sa = smem + bufidx * 16384;
    long a[4][2];
    #pragma unroll
    for (int rt = 0; rt < 4; rt++) {
      int row = wr * 64 + rt * 16 + lr;
      int sw = (row >> 2) & 3;
      #pragma unroll
      for (int m = 0; m < 2; m++)
        a[rt][m] = *(const long*)(sa + m * 4096 + row * 32 + ((g ^ sw) << 3));
    }
    __builtin_amdgcn_s_setprio(1);
    #pragma unroll
    for (int ct = 0; ct < 4; ct++) {
      int col = wc * 64 + ct * 16 + lr;
      int sw = (col >> 2) & 3;
      #pragma unroll
      for (int m = 0; m < 2; m++) {
        long b = *(const long*)(sa + 8192 + m * 4096 + col * 32 + ((g ^ sw) << 3));
        #pragma unroll
        for (int rt = 0; rt < 4; rt++)
          acc[rt][ct][m] =
              __builtin_amdgcn_mfma_f32_16x16x32_fp8_fp8(a[rt][m], b, acc[rt][ct][m], 0, 0, 0);
      }
    }
    __builtin_amdgcn_s_setprio(0);
  };

  // prologue: 3 stages in flight (12 vmem ops/wave)
  stage(0, 0); stage(1, 1); stage(2, 2);

  // steady state: wait vmcnt(8) -> stage(k) landed; never drain to 0 in-loop
  for (int k = 0; k < NITER - 3; k++) {
    asm volatile("s_waitcnt vmcnt(8)" ::: "memory");
    __builtin_amdgcn_s_barrier();
    stage((k + 3) & 3, k + 3);
    body(k & 3);
  }
  asm volatile("s_waitcnt vmcnt(8)" ::: "memory");
  __builtin_amdgcn_s_barrier();
  body((NITER - 3) & 3);
  asm volatile("s_waitcnt vmcnt(4)" ::: "memory");
  __builtin_amdgcn_s_barrier();
  body((NITER - 2) & 3);
  asm volatile("s_waitcnt vmcnt(0)" ::: "memory");
  __builtin_amdgcn_s_barrier();
  body((NITER - 1) & 3);

  // ---- epilogue: fixed-max (m=1) stats; plain sums + spread atomics ----
  // C/D layout: row = tile + g*4 + r, col = tile + lr
  #pragma unroll
  for (int rt = 0; rt < 4; rt++) {
    #pragma unroll
    for (int r = 0; r < 4; r++) {
      float e1 = 0.f, e2 = 0.f, sl = 0.f;
      #pragma unroll
      for (int ct = 0; ct < 4; ct++) {
        float s1 = acc[rt][ct][0][r], s2 = acc[rt][ct][1][r];
        float p = __expf(s1 - 1.0f);
        e1 += p; sl += p * (s1 - s2);
        e2 += __expf(s2 - 1.0f);
      }
      #pragma unroll
      for (int mk = 1; mk < 16; mk <<= 1) {
        e1 += __shfl_xor(e1, mk);
        e2 += __shfl_xor(e2, mk);
        sl += __shfl_xor(sl, mk);
      }
      if (lr == 0) {
        int row = rowbase + wr * 64 + rt * 16 + g * 4 + r;
        atomicAdd(&rowstats[row * 3 + 0], e1);
        atomicAdd(&rowstats[row * 3 + 1], e2);
        atomicAdd(&rowstats[row * 3 + 2], sl);
      }
    }
  }
  if (rb != cc) {  // transpose contribution for off-diagonal tiles
    #pragma unroll
    for (int ct = 0; ct < 4; ct++) {
      float e1 = 0.f, e2 = 0.f, sl = 0.f;
      #pragma unroll
      for (int rt = 0; rt < 4; rt++)
        #pragma unroll
        for (int r = 0; r < 4; r++) {
          float s1 = acc[rt][ct][0][r], s2 = acc[rt][ct][1][r];
          float p = __expf(s1 - 1.0f);
          e1 += p; sl += p * (s1 - s2);
          e2 += __expf(s2 - 1.0f);
        }
      e1 += __shfl_xor(e1, 16); e2 += __shfl_xor(e2, 16); sl += __shfl_xor(sl, 16);
      e1 += __shfl_xor(e1, 32); e2 += __shfl_xor(e2, 32); sl += __shfl_xor(sl, 32);
      if (g == 0) {
        int col = colbase + wc * 64 + ct * 16 + lr;
        atomicAdd(&rowstats[col * 3 + 0], e1);
        atomicAdd(&rowstats[col * 3 + 1], e2);
        atomicAdd(&rowstats[col * 3 + 2], sl);
      }
    }
  }
}

// ---------------- single-block finalize: row KLs + prep row term -> mean ----------------
__global__ __launch_bounds__(1024) void finalize_kernel(const float* __restrict__ rowstats,
                                                        const float* __restrict__ rowkl,
                                                        float* __restrict__ out) {
  __shared__ float buf[16];
  float s = 0.f;
  for (int r = threadIdx.x; r < N; r += 1024) {
    float e1 = rowstats[r * 3 + 0];
    float e2 = rowstats[r * 3 + 1];
    float sl = rowstats[r * 3 + 2];
    s += sl / e1 - (__logf(e1) - __logf(e2)) + rowkl[r];
  }
  #pragma unroll
  for (int o = 32; o > 0; o >>= 1) s += __shfl_xor(s, o);
  if ((threadIdx.x & 63) == 0) buf[threadIdx.x >> 6] = s;
  __syncthreads();
  if (threadIdx.x == 0) {
    float t = 0.f;
    #pragma unroll
    for (int i = 0; i < 16; i++) t += buf[i];
    out[0] = t * (1.0f / (float)N);
  }
}

// ---------------- launch ----------------
extern "C" void kernel_launch(void* const* d_in, const int* in_sizes, int n_in,
                              void* d_out, int out_size, void* d_ws, size_t ws_size,
                              hipStream_t stream) {
  const float* tgt = (const float*)d_in[0];
  const float* prd = (const float*)d_in[1];
  float* out = (float*)d_out;
  char* ws = (char*)d_ws;
  // ws layout: tn 4MB (blocked fp8) | pn 4MB | rowstats N*3 f32 | rowkl N f32
  uint8_t* tn = (uint8_t*)ws;
  uint8_t* pn = (uint8_t*)(ws + 4194304);
  float* rowstats = (float*)(ws + 8388608);
  float* rowkl = rowstats + N * 3;

  zero_kernel<<<(N * 3 + 255) / 256, 256, 0, stream>>>(rowstats);
  prep_kernel<<<N / 4, 256, 0, stream>>>(tgt, prd, tn, pn, rowkl);
  gram_kernel<<<NTRI, 256, 0, stream>>>(tn, pn, rowstats);
  finalize_kernel<<<1, 1024, 0, stream>>>(rowstats, rowkl, out);
}